// Round 3
// baseline (762.323 us; speedup 1.0000x reference)
//
#include <hip/hip_runtime.h>

// Shapes fixed by the reference: T=4, F=64, row = T*F = 256 elems.
#define TF 256

typedef __attribute__((ext_vector_type(8))) short short8;
typedef __attribute__((ext_vector_type(4))) float f32x4;

// ---------- bf16 helpers (fp32 <-> bf16, RNE) ----------
__device__ inline unsigned short f2bf(float x) {
  unsigned u = __float_as_uint(x);
  u += 0x7fffu + ((u >> 16) & 1u);
  return (unsigned short)(u >> 16);
}
__device__ inline unsigned pack2(unsigned short lo, unsigned short hi) {
  return (unsigned)lo | ((unsigned)hi << 16);
}
__device__ inline float bflo(unsigned u) { return __uint_as_float(u << 16); }
__device__ inline float bfhi(unsigned u) { return __uint_as_float(u & 0xffff0000u); }

__global__ void zero_kernel(int* __restrict__ p, int n) {
  int i = blockIdx.x * blockDim.x + threadIdx.x;
  if (i < n) p[i] = 0;
}

__global__ void hist_kernel(const int* __restrict__ dst, int* __restrict__ indeg, int E) {
  int e = blockIdx.x * blockDim.x + threadIdx.x;
  if (e < E) atomicAdd(&indeg[dst[e]], 1);
}

// ---------- hierarchical scan ----------
__global__ __launch_bounds__(1024) void scan_part1(const int* __restrict__ indeg,
                                                   int* __restrict__ partials, int n) {
  __shared__ int wsum[16];
  const int tid = threadIdx.x;
  const int lane = tid & 63;
  const int wid = tid >> 6;
  int i = blockIdx.x * 1024 + tid;
  int s = (i < n) ? indeg[i] : 0;
  #pragma unroll
  for (int o = 1; o < 64; o <<= 1) s += __shfl_xor(s, o, 64);
  if (lane == 0) wsum[wid] = s;
  __syncthreads();
  if (tid == 0) {
    int acc = 0;
    #pragma unroll
    for (int w = 0; w < 16; ++w) acc += wsum[w];
    partials[blockIdx.x] = acc;
  }
}

__global__ __launch_bounds__(64) void scan_part2(const int* __restrict__ partials,
                                                 int* __restrict__ base,
                                                 int* __restrict__ offsets, int nb, int n) {
  const int i = threadIdx.x;
  int v = (i < nb) ? partials[i] : 0;
  int s = v;
  #pragma unroll
  for (int o = 1; o < 64; o <<= 1) {
    int t = __shfl_up(s, o, 64);
    if (i >= o) s += t;
  }
  if (i < nb) base[i] = s - v;
  if (i == nb - 1) offsets[n] = s;
}

__global__ __launch_bounds__(1024) void scan_part3(const int* __restrict__ indeg,
                                                   const int* __restrict__ base,
                                                   int* __restrict__ offsets,
                                                   int* __restrict__ cursor, int n) {
  __shared__ int wsum[16];
  const int tid = threadIdx.x;
  const int lane = tid & 63;
  const int wid = tid >> 6;
  int i = blockIdx.x * 1024 + tid;
  int v = (i < n) ? indeg[i] : 0;
  int s = v;
  #pragma unroll
  for (int o = 1; o < 64; o <<= 1) {
    int t = __shfl_up(s, o, 64);
    if (lane >= o) s += t;
  }
  if (lane == 63) wsum[wid] = s;
  __syncthreads();
  if (tid == 0) {
    int acc = 0;
    #pragma unroll
    for (int w = 0; w < 16; ++w) { int t = wsum[w]; wsum[w] = acc; acc += t; }
  }
  __syncthreads();
  int excl = s - v + wsum[wid] + base[blockIdx.x];
  if (i < n) { offsets[i] = excl; cursor[i] = excl; }
}

__global__ void fill_kernel(const int* __restrict__ src, const int* __restrict__ dst,
                            const float* __restrict__ ew, int* __restrict__ cursor,
                            int* __restrict__ csr_src, float4* __restrict__ csr_w, int E) {
  int e = blockIdx.x * blockDim.x + threadIdx.x;
  if (e >= E) return;
  int d = dst[e];
  int pos = atomicAdd(&cursor[d], 1);
  csr_src[pos] = src[e];
  float4 w;
  w.x = ew[0 * E + e];
  w.y = ew[1 * E + e];
  w.z = ew[2 * E + e];
  w.w = ew[3 * E + e];
  csr_w[pos] = w;
}

// h0_bf16 = bf16(node_features + pe[identities[t]]); 4 elems/thread
__global__ void prep_kernel(const float* __restrict__ x, const float* __restrict__ pe,
                            const int* __restrict__ ids, uint2* __restrict__ h0, int n4) {
  int i = blockIdx.x * blockDim.x + threadIdx.x;
  const int stride = gridDim.x * blockDim.x;
  for (; i < n4; i += stride) {
    int e0 = (i << 2) & (TF - 1);
    int t = e0 >> 6;
    int f4 = e0 & 63;
    float4 v = reinterpret_cast<const float4*>(x)[i];
    float4 p = *reinterpret_cast<const float4*>(&pe[ids[t] * 64 + f4]);
    uint2 o;
    o.x = pack2(f2bf(v.x + p.x), f2bf(v.y + p.y));
    o.y = pack2(f2bf(v.z + p.z), f2bf(v.w + p.w));
    h0[i] = o;
  }
}

// One wave per node; lane covers elems [lane*4, lane*4+4) of the 256-wide bf16 row.
// LAYER 1 applies relu(y*scale+shift) (layer-0 BN) on the fly.
template <int LAYER>
__global__ __launch_bounds__(256) void aggregate_kernel(
    const uint2* __restrict__ h_in, const int* __restrict__ offsets,
    const int* __restrict__ csr_src, const float* __restrict__ csr_w,
    const float* __restrict__ scale, const float* __restrict__ shiftv,
    uint2* __restrict__ agg, int n_nodes) {
  const int lane = threadIdx.x & 63;
  const int wid = threadIdx.x >> 6;
  const int v = blockIdx.x * 4 + wid;
  if (v >= n_nodes) return;
  const int t = lane >> 4;
  const int f4 = (lane & 15) << 2;

  float4 sc = make_float4(0.f, 0.f, 0.f, 0.f);
  float4 sh = make_float4(0.f, 0.f, 0.f, 0.f);
  if (LAYER == 1) {
    sc = *reinterpret_cast<const float4*>(&scale[f4]);
    sh = *reinterpret_cast<const float4*>(&shiftv[f4]);
  }

  float a0 = 0.f, a1 = 0.f, a2 = 0.f, a3 = 0.f;

  auto body = [&](uint2 q, float w) {
    float x0 = bflo(q.x), x1 = bfhi(q.x), x2 = bflo(q.y), x3 = bfhi(q.y);
    if (LAYER == 1) {
      x0 = fmaxf(0.f, fmaf(x0, sc.x, sh.x));
      x1 = fmaxf(0.f, fmaf(x1, sc.y, sh.y));
      x2 = fmaxf(0.f, fmaf(x2, sc.z, sh.z));
      x3 = fmaxf(0.f, fmaf(x3, sc.w, sh.w));
    }
    a0 = fmaf(w, x0, a0);
    a1 = fmaf(w, x1, a1);
    a2 = fmaf(w, x2, a2);
    a3 = fmaf(w, x3, a3);
  };

  const int beg = offsets[v];
  const int end = offsets[v + 1];
  int i = beg;
  for (; i + 2 <= end; i += 2) {
    const int s0 = csr_src[i];
    const int s1 = csr_src[i + 1];
    const float w0 = csr_w[i * 4 + t];
    const float w1 = csr_w[i * 4 + 4 + t];
    const uint2 q0 = h_in[(size_t)s0 * 64 + lane];
    const uint2 q1 = h_in[(size_t)s1 * 64 + lane];
    body(q0, w0);
    body(q1, w1);
  }
  if (i < end) {
    const int s0 = csr_src[i];
    const float w0 = csr_w[i * 4 + t];
    body(h_in[(size_t)s0 * 64 + lane], w0);
  }

  uint2 o;
  o.x = pack2(f2bf(a0), f2bf(a1));
  o.y = pack2(f2bf(a2), f2bf(a3));
  agg[(size_t)v * 64 + lane] = o;
}

// Pre-pack W (fp32 64x64) into MFMA B-fragment layout as bf16.
// frag = c*2+h (c: col-tile 0..3, h: K-half 0..1); lane holds 8 elems
// B[k = h*32 + (lane>>4)*8 + i][col = c*16 + (lane&15)].
__global__ __launch_bounds__(512) void wfrag_kernel(const float* __restrict__ W0,
                                                    const float* __restrict__ W1,
                                                    short* __restrict__ wf0,
                                                    short* __restrict__ wf1) {
  const int frag = threadIdx.x >> 6, lane = threadIdx.x & 63;
  const int c = frag >> 1, h = frag & 1;
  const int n = (c << 4) + (lane & 15);
  const int k0 = h * 32 + ((lane >> 4) << 3);
  short* o0 = wf0 + frag * 512 + lane * 8;
  short* o1 = wf1 + frag * 512 + lane * 8;
  #pragma unroll
  for (int i = 0; i < 8; ++i) {
    o0[i] = (short)f2bf(W0[(k0 + i) * 64 + n]);
    o1[i] = (short)f2bf(W1[(k0 + i) * 64 + n]);
  }
}

// y[r,f] = agg_bf16[r,:] @ W ; 8 MFMAs per 16-row block per wave.
// D layout (m89): col = lane&15, row = (lane>>4)*4 + reg; base%16==0 -> reg == time t.
// Emits per-block partials: part[blk*320 + t*64+f] = sum_rows y, part[blk*320+256+f] = sum y^2.
// LAYER 0 stores y as bf16 (feeds layer-1 gather); LAYER 1 stores fp32 to d_out.
template <int LAYER>
__global__ __launch_bounds__(256) void mfma_matmul_kernel(
    const unsigned short* __restrict__ aggb, const short* __restrict__ wf,
    unsigned short* __restrict__ y_bf, float* __restrict__ y_f32,
    float* __restrict__ part, int R) {
  const int tid = threadIdx.x;
  const int lane = tid & 63;
  const int wid = tid >> 6;

  short8 bfr[8];
  #pragma unroll
  for (int g = 0; g < 8; ++g)
    bfr[g] = *reinterpret_cast<const short8*>(wf + g * 512 + lane * 8);

  f32x4 csum[4];
  float ssq[4];
  #pragma unroll
  for (int c = 0; c < 4; ++c) { csum[c] = (f32x4){0.f, 0.f, 0.f, 0.f}; ssq[c] = 0.f; }

  const int nrb = (R + 15) >> 4;
  const int k0 = (lane >> 4) << 3;  // first-half k offset for this lane
  for (int rb = blockIdx.x * 4 + wid; rb < nrb; rb += gridDim.x * 4) {
    const int base = rb << 4;
    const int row = base + (lane & 15);
    short8 a0 = (short8){0, 0, 0, 0, 0, 0, 0, 0};
    short8 a1 = a0;
    if (row < R) {
      const short8* ap = reinterpret_cast<const short8*>(aggb + (size_t)row * 64 + k0);
      a0 = ap[0];
      a1 = ap[4];  // +32 elems (second K-half)
    }
    f32x4 acc[4];
    #pragma unroll
    for (int c = 0; c < 4; ++c) {
      acc[c] = (f32x4){0.f, 0.f, 0.f, 0.f};
      acc[c] = __builtin_amdgcn_mfma_f32_16x16x32_bf16(a0, bfr[c * 2 + 0], acc[c], 0, 0, 0);
      acc[c] = __builtin_amdgcn_mfma_f32_16x16x32_bf16(a1, bfr[c * 2 + 1], acc[c], 0, 0, 0);
    }
    const int rbase = base + ((lane >> 4) << 2);
    #pragma unroll
    for (int c = 0; c < 4; ++c) {
      const int col = (c << 4) + (lane & 15);
      #pragma unroll
      for (int i = 0; i < 4; ++i) {
        const int r2 = rbase + i;
        if (r2 < R) {
          const float val = acc[c][i];
          if (LAYER == 0) y_bf[(size_t)r2 * 64 + col] = f2bf(val);
          else            y_f32[(size_t)r2 * 64 + col] = val;
          csum[c][i] += val;
          ssq[c] += val * val;
        }
      }
    }
  }

  // reduce over the 4 lane-groups that share a column (lanes l, l+16, l+32, l+48)
  #pragma unroll
  for (int c = 0; c < 4; ++c) {
    #pragma unroll
    for (int i = 0; i < 4; ++i) {
      float v = csum[c][i];
      v += __shfl_xor(v, 16, 64);
      v += __shfl_xor(v, 32, 64);
      csum[c][i] = v;
    }
    float q = ssq[c];
    q += __shfl_xor(q, 16, 64);
    q += __shfl_xor(q, 32, 64);
    ssq[c] = q;
  }
  __shared__ float lcs[4][256];
  __shared__ float lsq[4][64];
  if (lane < 16) {
    #pragma unroll
    for (int c = 0; c < 4; ++c) {
      #pragma unroll
      for (int i = 0; i < 4; ++i) lcs[wid][i * 64 + (c << 4) + lane] = csum[c][i];
      lsq[wid][(c << 4) + lane] = ssq[c];
    }
  }
  __syncthreads();
  float s = lcs[0][tid] + lcs[1][tid] + lcs[2][tid] + lcs[3][tid];
  part[(size_t)blockIdx.x * 320 + tid] = s;
  if (tid < 64)
    part[(size_t)blockIdx.x * 320 + 256 + tid] =
        lsq[0][tid] + lsq[1][tid] + lsq[2][tid] + lsq[3][tid];
}

// layer-0 BN params from block partials
__global__ __launch_bounds__(256) void bn_params_kernel(
    const float* __restrict__ part, int nblk, const float* __restrict__ g,
    const float* __restrict__ b, float* __restrict__ scale, float* __restrict__ shiftv,
    float inv_count) {
  __shared__ float lds[256];
  const int tid = threadIdx.x;
  float s = 0.f;
  for (int bk = 0; bk < nblk; ++bk) s += part[(size_t)bk * 320 + tid];
  lds[tid] = s;
  __syncthreads();
  if (tid < 64) {
    float sum = lds[tid] + lds[64 + tid] + lds[128 + tid] + lds[192 + tid];
    float q = 0.f;
    for (int bk = 0; bk < nblk; ++bk) q += part[(size_t)bk * 320 + 256 + tid];
    float mean = sum * inv_count;
    float var = q * inv_count - mean * mean;
    float sc = g[tid] * rsqrtf(var + 1e-5f);
    scale[tid] = sc;
    shiftv[tid] = fmaf(-mean, sc, b[tid]);
  }
}

// layer-1: readout = colsum_y/N (linearity: mean(agg)@W == mean(agg@W)) + BN params
__global__ __launch_bounds__(256) void finalize_kernel(
    const float* __restrict__ part, int nblk, const float* __restrict__ g,
    const float* __restrict__ b, float* __restrict__ scale, float* __restrict__ shiftv,
    float inv_count, float* __restrict__ out_readout, float invN) {
  __shared__ float lds[256];
  const int tid = threadIdx.x;
  float cs = 0.f;
  for (int bk = 0; bk < nblk; ++bk) cs += part[(size_t)bk * 320 + tid];
  out_readout[tid] = cs * invN;
  lds[tid] = cs;
  __syncthreads();
  if (tid < 64) {
    float sum = lds[tid] + lds[64 + tid] + lds[128 + tid] + lds[192 + tid];
    float q = 0.f;
    for (int bk = 0; bk < nblk; ++bk) q += part[(size_t)bk * 320 + 256 + tid];
    float mean = sum * inv_count;
    float var = q * inv_count - mean * mean;
    float sc = g[tid] * rsqrtf(var + 1e-5f);
    scale[tid] = sc;
    shiftv[tid] = fmaf(-mean, sc, b[tid]);
  }
}

__global__ void bn_relu_kernel(float* __restrict__ y, const float* __restrict__ scale,
                               const float* __restrict__ shiftv, int nvec4) {
  int i = blockIdx.x * blockDim.x + threadIdx.x;
  const int stride = gridDim.x * blockDim.x;
  for (; i < nvec4; i += stride) {
    float4 v = reinterpret_cast<float4*>(y)[i];
    int f4 = (i << 2) & 63;
    float4 sc = *reinterpret_cast<const float4*>(&scale[f4]);
    float4 sh = *reinterpret_cast<const float4*>(&shiftv[f4]);
    v.x = fmaxf(0.f, fmaf(v.x, sc.x, sh.x));
    v.y = fmaxf(0.f, fmaf(v.y, sc.y, sh.y));
    v.z = fmaxf(0.f, fmaf(v.z, sc.z, sh.z));
    v.w = fmaxf(0.f, fmaf(v.w, sc.w, sh.w));
    reinterpret_cast<float4*>(y)[i] = v;
  }
}

extern "C" void kernel_launch(void* const* d_in, const int* in_sizes, int n_in,
                              void* d_out, int out_size, void* d_ws, size_t ws_size,
                              hipStream_t stream) {
  const float* node_features = (const float*)d_in[0];
  const float* edges_weight  = (const float*)d_in[1];
  const int*   identities    = (const int*)d_in[2];
  const int*   edge_src      = (const int*)d_in[3];
  const int*   edge_dst      = (const int*)d_in[4];
  const float* pe            = (const float*)d_in[5];
  const float* W0            = (const float*)d_in[6];
  const float* W1            = (const float*)d_in[7];
  const float* g0            = (const float*)d_in[8];
  const float* b0            = (const float*)d_in[9];
  const float* g1            = (const float*)d_in[10];
  const float* b1            = (const float*)d_in[11];

  const int T = in_sizes[2];            // 4
  const int E = in_sizes[3];            // 800000
  const int F = in_sizes[8];            // 64
  const int N = in_sizes[0] / (T * F);  // 50000
  const int R = N * T;                  // 200000

  float* out = (float*)d_out;
  float* out_h = out;                            // (N,T,F) fp32
  float* out_readout = out + (size_t)N * T * F;  // (T,F)

  // ---- workspace layout ----
  char* ws = (char*)d_ws;
  size_t off = 0;
  auto alloc = [&](size_t bytes) -> void* {
    off = (off + 255) & ~(size_t)255;
    void* p = ws + off;
    off += bytes;
    return p;
  };
  int*    indeg    = (int*)alloc((size_t)N * sizeof(int));
  int*    partials = (int*)alloc(64 * sizeof(int));
  int*    base_    = (int*)alloc(64 * sizeof(int));
  int*    offsets  = (int*)alloc(((size_t)N + 1) * sizeof(int));
  int*    cursor   = (int*)alloc((size_t)N * sizeof(int));
  int*    csr_src  = (int*)alloc((size_t)E * sizeof(int));
  float4* csr_w    = (float4*)alloc((size_t)E * sizeof(float4));
  unsigned short* h0b  = (unsigned short*)alloc((size_t)N * TF * 2);  // reused as y0b
  unsigned short* aggb = (unsigned short*)alloc((size_t)N * TF * 2);
  short* wf0 = (short*)alloc(8 * 512 * sizeof(short));
  short* wf1 = (short*)alloc(8 * 512 * sizeof(short));
  const int MMB = 512;  // mfma matmul grid
  float* mm_part = (float*)alloc((size_t)MMB * 320 * sizeof(float));
  float* scale0 = (float*)alloc(64 * sizeof(float));
  float* shift0 = (float*)alloc(64 * sizeof(float));
  float* scale1 = (float*)alloc(64 * sizeof(float));
  float* shift1 = (float*)alloc(64 * sizeof(float));
  (void)ws_size;

  const int nb = (N + 1023) / 1024;  // <=64

  // ---- CSR build ----
  hipLaunchKernelGGL(zero_kernel, dim3((N + 255) / 256), dim3(256), 0, stream, indeg, N);
  hipLaunchKernelGGL(hist_kernel, dim3((E + 255) / 256), dim3(256), 0, stream, edge_dst, indeg, E);
  hipLaunchKernelGGL(scan_part1, dim3(nb), dim3(1024), 0, stream, indeg, partials, N);
  hipLaunchKernelGGL(scan_part2, dim3(1), dim3(64), 0, stream, partials, base_, offsets, nb, N);
  hipLaunchKernelGGL(scan_part3, dim3(nb), dim3(1024), 0, stream, indeg, base_, offsets, cursor, N);
  hipLaunchKernelGGL(fill_kernel, dim3((E + 255) / 256), dim3(256), 0, stream,
                     edge_src, edge_dst, edges_weight, cursor, csr_src, csr_w, E);

  // ---- W fragments + prep ----
  hipLaunchKernelGGL(wfrag_kernel, dim3(1), dim3(512), 0, stream, W0, W1, wf0, wf1);
  hipLaunchKernelGGL(prep_kernel, dim3(2048), dim3(256), 0, stream,
                     node_features, pe, identities, (uint2*)h0b, (N * TF) / 4);

  const int agg_blocks = (N + 3) / 4;

  // ---- layer 0 ----
  hipLaunchKernelGGL((aggregate_kernel<0>), dim3(agg_blocks), dim3(256), 0, stream,
                     (const uint2*)h0b, offsets, csr_src, (const float*)csr_w,
                     nullptr, nullptr, (uint2*)aggb, N);
  hipLaunchKernelGGL((mfma_matmul_kernel<0>), dim3(MMB), dim3(256), 0, stream,
                     aggb, wf0, h0b /*y0b*/, nullptr, mm_part, R);
  hipLaunchKernelGGL(bn_params_kernel, dim3(1), dim3(256), 0, stream,
                     mm_part, MMB, g0, b0, scale0, shift0, 1.0f / (float)R);

  // ---- layer 1 (BN0+ReLU fused into gather) ----
  hipLaunchKernelGGL((aggregate_kernel<1>), dim3(agg_blocks), dim3(256), 0, stream,
                     (const uint2*)h0b /*y0b*/, offsets, csr_src, (const float*)csr_w,
                     scale0, shift0, (uint2*)aggb, N);
  hipLaunchKernelGGL((mfma_matmul_kernel<1>), dim3(MMB), dim3(256), 0, stream,
                     aggb, wf1, nullptr, out_h, mm_part, R);
  hipLaunchKernelGGL(finalize_kernel, dim3(1), dim3(256), 0, stream,
                     mm_part, MMB, g1, b1, scale1, shift1, 1.0f / (float)R,
                     out_readout, 1.0f / (float)N);

  // ---- final BN1 + ReLU in place ----
  hipLaunchKernelGGL(bn_relu_kernel, dim3(2048), dim3(256), 0, stream,
                     out_h, scale1, shift1, (R * F) >> 2);
}

// Round 4
// 295.569 us; speedup vs baseline: 2.5792x; 2.5792x over previous
//
#include <hip/hip_runtime.h>

// Shapes fixed by the reference: T=4, F=64, row = T*F = 256 elems.
#define TF 256

typedef __attribute__((ext_vector_type(8))) short short8;
typedef __attribute__((ext_vector_type(4))) float f32x4;

// ---------- bf16 helpers (fp32 <-> bf16, RNE) ----------
__device__ inline unsigned short f2bf(float x) {
  unsigned u = __float_as_uint(x);
  u += 0x7fffu + ((u >> 16) & 1u);
  return (unsigned short)(u >> 16);
}
__device__ inline unsigned pack2(unsigned short lo, unsigned short hi) {
  return (unsigned)lo | ((unsigned)hi << 16);
}
__device__ inline float bflo(unsigned u) { return __uint_as_float(u << 16); }
__device__ inline float bfhi(unsigned u) { return __uint_as_float(u & 0xffff0000u); }

__global__ void zero_kernel(int* __restrict__ p, int n) {
  int i = blockIdx.x * blockDim.x + threadIdx.x;
  if (i < n) p[i] = 0;
}

__global__ void hist_kernel(const int* __restrict__ dst, int* __restrict__ indeg, int E) {
  int e = blockIdx.x * blockDim.x + threadIdx.x;
  if (e < E) atomicAdd(&indeg[dst[e]], 1);
}

// ---------- hierarchical scan ----------
__global__ __launch_bounds__(1024) void scan_part1(const int* __restrict__ indeg,
                                                   int* __restrict__ partials, int n) {
  __shared__ int wsum[16];
  const int tid = threadIdx.x;
  const int lane = tid & 63;
  const int wid = tid >> 6;
  int i = blockIdx.x * 1024 + tid;
  int s = (i < n) ? indeg[i] : 0;
  #pragma unroll
  for (int o = 1; o < 64; o <<= 1) s += __shfl_xor(s, o, 64);
  if (lane == 0) wsum[wid] = s;
  __syncthreads();
  if (tid == 0) {
    int acc = 0;
    #pragma unroll
    for (int w = 0; w < 16; ++w) acc += wsum[w];
    partials[blockIdx.x] = acc;
  }
}

__global__ __launch_bounds__(64) void scan_part2(const int* __restrict__ partials,
                                                 int* __restrict__ base,
                                                 int* __restrict__ offsets, int nb, int n) {
  const int i = threadIdx.x;
  int v = (i < nb) ? partials[i] : 0;
  int s = v;
  #pragma unroll
  for (int o = 1; o < 64; o <<= 1) {
    int t = __shfl_up(s, o, 64);
    if (i >= o) s += t;
  }
  if (i < nb) base[i] = s - v;
  if (i == nb - 1) offsets[n] = s;
}

__global__ __launch_bounds__(1024) void scan_part3(const int* __restrict__ indeg,
                                                   const int* __restrict__ base,
                                                   int* __restrict__ offsets,
                                                   int* __restrict__ cursor, int n) {
  __shared__ int wsum[16];
  const int tid = threadIdx.x;
  const int lane = tid & 63;
  const int wid = tid >> 6;
  int i = blockIdx.x * 1024 + tid;
  int v = (i < n) ? indeg[i] : 0;
  int s = v;
  #pragma unroll
  for (int o = 1; o < 64; o <<= 1) {
    int t = __shfl_up(s, o, 64);
    if (lane >= o) s += t;
  }
  if (lane == 63) wsum[wid] = s;
  __syncthreads();
  if (tid == 0) {
    int acc = 0;
    #pragma unroll
    for (int w = 0; w < 16; ++w) { int t = wsum[w]; wsum[w] = acc; acc += t; }
  }
  __syncthreads();
  int excl = s - v + wsum[wid] + base[blockIdx.x];
  if (i < n) { offsets[i] = excl; cursor[i] = excl; }
}

__global__ void fill_kernel(const int* __restrict__ src, const int* __restrict__ dst,
                            const float* __restrict__ ew, int* __restrict__ cursor,
                            int* __restrict__ csr_src, float4* __restrict__ csr_w, int E) {
  int e = blockIdx.x * blockDim.x + threadIdx.x;
  if (e >= E) return;
  int d = dst[e];
  int pos = atomicAdd(&cursor[d], 1);
  csr_src[pos] = src[e];
  float4 w;
  w.x = ew[0 * E + e];
  w.y = ew[1 * E + e];
  w.z = ew[2 * E + e];
  w.w = ew[3 * E + e];
  csr_w[pos] = w;
}

// h0_bf16 = bf16(node_features + pe[identities[t]]); 4 elems/thread
__global__ void prep_kernel(const float* __restrict__ x, const float* __restrict__ pe,
                            const int* __restrict__ ids, uint2* __restrict__ h0, int n4) {
  int i = blockIdx.x * blockDim.x + threadIdx.x;
  const int stride = gridDim.x * blockDim.x;
  for (; i < n4; i += stride) {
    int e0 = (i << 2) & (TF - 1);
    int t = e0 >> 6;
    int f4 = e0 & 63;
    float4 v = reinterpret_cast<const float4*>(x)[i];
    float4 p = *reinterpret_cast<const float4*>(&pe[ids[t] * 64 + f4]);
    uint2 o;
    o.x = pack2(f2bf(v.x + p.x), f2bf(v.y + p.y));
    o.y = pack2(f2bf(v.z + p.z), f2bf(v.w + p.w));
    h0[i] = o;
  }
}

// One wave per node; lane covers elems [lane*4, lane*4+4) of the 256-wide bf16 row.
// LAYER 1 applies relu(y*scale+shift) (layer-0 BN) on the fly.
template <int LAYER>
__global__ __launch_bounds__(256) void aggregate_kernel(
    const uint2* __restrict__ h_in, const int* __restrict__ offsets,
    const int* __restrict__ csr_src, const float* __restrict__ csr_w,
    const float* __restrict__ scale, const float* __restrict__ shiftv,
    uint2* __restrict__ agg, int n_nodes) {
  const int lane = threadIdx.x & 63;
  const int wid = threadIdx.x >> 6;
  const int v = blockIdx.x * 4 + wid;
  if (v >= n_nodes) return;
  const int t = lane >> 4;
  const int f4 = (lane & 15) << 2;

  float4 sc = make_float4(0.f, 0.f, 0.f, 0.f);
  float4 sh = make_float4(0.f, 0.f, 0.f, 0.f);
  if (LAYER == 1) {
    sc = *reinterpret_cast<const float4*>(&scale[f4]);
    sh = *reinterpret_cast<const float4*>(&shiftv[f4]);
  }

  float a0 = 0.f, a1 = 0.f, a2 = 0.f, a3 = 0.f;

  auto body = [&](uint2 q, float w) {
    float x0 = bflo(q.x), x1 = bfhi(q.x), x2 = bflo(q.y), x3 = bfhi(q.y);
    if (LAYER == 1) {
      x0 = fmaxf(0.f, fmaf(x0, sc.x, sh.x));
      x1 = fmaxf(0.f, fmaf(x1, sc.y, sh.y));
      x2 = fmaxf(0.f, fmaf(x2, sc.z, sh.z));
      x3 = fmaxf(0.f, fmaf(x3, sc.w, sh.w));
    }
    a0 = fmaf(w, x0, a0);
    a1 = fmaf(w, x1, a1);
    a2 = fmaf(w, x2, a2);
    a3 = fmaf(w, x3, a3);
  };

  const int beg = offsets[v];
  const int end = offsets[v + 1];
  int i = beg;
  for (; i + 2 <= end; i += 2) {
    const int s0 = csr_src[i];
    const int s1 = csr_src[i + 1];
    const float w0 = csr_w[i * 4 + t];
    const float w1 = csr_w[i * 4 + 4 + t];
    const uint2 q0 = h_in[(size_t)s0 * 64 + lane];
    const uint2 q1 = h_in[(size_t)s1 * 64 + lane];
    body(q0, w0);
    body(q1, w1);
  }
  if (i < end) {
    const int s0 = csr_src[i];
    const float w0 = csr_w[i * 4 + t];
    body(h_in[(size_t)s0 * 64 + lane], w0);
  }

  uint2 o;
  o.x = pack2(f2bf(a0), f2bf(a1));
  o.y = pack2(f2bf(a2), f2bf(a3));
  agg[(size_t)v * 64 + lane] = o;
}

// Pre-pack W (fp32 64x64) into MFMA B-fragment layout as bf16.
__global__ __launch_bounds__(512) void wfrag_kernel(const float* __restrict__ W0,
                                                    const float* __restrict__ W1,
                                                    short* __restrict__ wf0,
                                                    short* __restrict__ wf1) {
  const int frag = threadIdx.x >> 6, lane = threadIdx.x & 63;
  const int c = frag >> 1, h = frag & 1;
  const int n = (c << 4) + (lane & 15);
  const int k0 = h * 32 + ((lane >> 4) << 3);
  short* o0 = wf0 + frag * 512 + lane * 8;
  short* o1 = wf1 + frag * 512 + lane * 8;
  #pragma unroll
  for (int i = 0; i < 8; ++i) {
    o0[i] = (short)f2bf(W0[(k0 + i) * 64 + n]);
    o1[i] = (short)f2bf(W1[(k0 + i) * 64 + n]);
  }
}

// y[r,f] = agg_bf16[r,:] @ W ; 8 MFMAs per 16-row block per wave.
// Emits per-block partials: part[blk*320 + t*64+f] = sum_rows y, part[blk*320+256+f] = sum y^2.
template <int LAYER>
__global__ __launch_bounds__(256) void mfma_matmul_kernel(
    const unsigned short* __restrict__ aggb, const short* __restrict__ wf,
    unsigned short* __restrict__ y_bf, float* __restrict__ y_f32,
    float* __restrict__ part, int R) {
  const int tid = threadIdx.x;
  const int lane = tid & 63;
  const int wid = tid >> 6;

  short8 bfr[8];
  #pragma unroll
  for (int g = 0; g < 8; ++g)
    bfr[g] = *reinterpret_cast<const short8*>(wf + g * 512 + lane * 8);

  f32x4 csum[4];
  float ssq[4];
  #pragma unroll
  for (int c = 0; c < 4; ++c) { csum[c] = (f32x4){0.f, 0.f, 0.f, 0.f}; ssq[c] = 0.f; }

  const int nrb = (R + 15) >> 4;
  const int k0 = (lane >> 4) << 3;
  for (int rb = blockIdx.x * 4 + wid; rb < nrb; rb += gridDim.x * 4) {
    const int base = rb << 4;
    const int row = base + (lane & 15);
    short8 a0 = (short8){0, 0, 0, 0, 0, 0, 0, 0};
    short8 a1 = a0;
    if (row < R) {
      const short8* ap = reinterpret_cast<const short8*>(aggb + (size_t)row * 64 + k0);
      a0 = ap[0];
      a1 = ap[4];
    }
    f32x4 acc[4];
    #pragma unroll
    for (int c = 0; c < 4; ++c) {
      acc[c] = (f32x4){0.f, 0.f, 0.f, 0.f};
      acc[c] = __builtin_amdgcn_mfma_f32_16x16x32_bf16(a0, bfr[c * 2 + 0], acc[c], 0, 0, 0);
      acc[c] = __builtin_amdgcn_mfma_f32_16x16x32_bf16(a1, bfr[c * 2 + 1], acc[c], 0, 0, 0);
    }
    const int rbase = base + ((lane >> 4) << 2);
    #pragma unroll
    for (int c = 0; c < 4; ++c) {
      const int col = (c << 4) + (lane & 15);
      #pragma unroll
      for (int i = 0; i < 4; ++i) {
        const int r2 = rbase + i;
        if (r2 < R) {
          const float val = acc[c][i];
          if (LAYER == 0) y_bf[(size_t)r2 * 64 + col] = f2bf(val);
          else            y_f32[(size_t)r2 * 64 + col] = val;
          csum[c][i] += val;
          ssq[c] += val * val;
        }
      }
    }
  }

  #pragma unroll
  for (int c = 0; c < 4; ++c) {
    #pragma unroll
    for (int i = 0; i < 4; ++i) {
      float v = csum[c][i];
      v += __shfl_xor(v, 16, 64);
      v += __shfl_xor(v, 32, 64);
      csum[c][i] = v;
    }
    float q = ssq[c];
    q += __shfl_xor(q, 16, 64);
    q += __shfl_xor(q, 32, 64);
    ssq[c] = q;
  }
  __shared__ float lcs[4][256];
  __shared__ float lsq[4][64];
  if (lane < 16) {
    #pragma unroll
    for (int c = 0; c < 4; ++c) {
      #pragma unroll
      for (int i = 0; i < 4; ++i) lcs[wid][i * 64 + (c << 4) + lane] = csum[c][i];
      lsq[wid][(c << 4) + lane] = ssq[c];
    }
  }
  __syncthreads();
  float s = lcs[0][tid] + lcs[1][tid] + lcs[2][tid] + lcs[3][tid];
  part[(size_t)blockIdx.x * 320 + tid] = s;
  if (tid < 64)
    part[(size_t)blockIdx.x * 320 + 256 + tid] =
        lsq[0][tid] + lsq[1][tid] + lsq[2][tid] + lsq[3][tid];
}

// Parallel deterministic reduce of part[nblk][320] -> red[320].
// Block b owns 16 columns; 64 threads/column stride over nblk; LDS tree over rows.
__global__ __launch_bounds__(1024) void reduce_part_kernel(const float* __restrict__ part,
                                                           float* __restrict__ red, int nblk) {
  __shared__ float lds[1024];
  const int tid = threadIdx.x;
  const int col = blockIdx.x * 16 + (tid & 15);
  const int r = tid >> 4;  // 0..63
  float s = 0.f;
  for (int bk = r; bk < nblk; bk += 64) s += part[(size_t)bk * 320 + col];
  lds[tid] = s;
  __syncthreads();
  #pragma unroll
  for (int off = 512; off >= 16; off >>= 1) {
    if (tid < off) lds[tid] += lds[tid + off];
    __syncthreads();
  }
  if (tid < 16) red[col] = lds[tid];
}

// layer-0 BN params from red[320]
__global__ __launch_bounds__(64) void bn_from_red_kernel(
    const float* __restrict__ red, const float* __restrict__ g, const float* __restrict__ b,
    float* __restrict__ scale, float* __restrict__ shiftv, float inv_count) {
  const int f = threadIdx.x;
  float sum = red[f] + red[64 + f] + red[128 + f] + red[192 + f];
  float mean = sum * inv_count;
  float var = red[256 + f] * inv_count - mean * mean;
  float sc = g[f] * rsqrtf(var + 1e-5f);
  scale[f] = sc;
  shiftv[f] = fmaf(-mean, sc, b[f]);
}

// layer-1: readout = red[0:256]/N (mean(agg)@W == mean(agg@W)) + BN params
__global__ __launch_bounds__(256) void finalize_from_red_kernel(
    const float* __restrict__ red, const float* __restrict__ g, const float* __restrict__ b,
    float* __restrict__ scale, float* __restrict__ shiftv, float inv_count,
    float* __restrict__ out_readout, float invN) {
  const int tid = threadIdx.x;
  out_readout[tid] = red[tid] * invN;
  if (tid < 64) {
    float sum = red[tid] + red[64 + tid] + red[128 + tid] + red[192 + tid];
    float mean = sum * inv_count;
    float var = red[256 + tid] * inv_count - mean * mean;
    float sc = g[tid] * rsqrtf(var + 1e-5f);
    scale[tid] = sc;
    shiftv[tid] = fmaf(-mean, sc, b[tid]);
  }
}

__global__ void bn_relu_kernel(float* __restrict__ y, const float* __restrict__ scale,
                               const float* __restrict__ shiftv, int nvec4) {
  int i = blockIdx.x * blockDim.x + threadIdx.x;
  const int stride = gridDim.x * blockDim.x;
  for (; i < nvec4; i += stride) {
    float4 v = reinterpret_cast<float4*>(y)[i];
    int f4 = (i << 2) & 63;
    float4 sc = *reinterpret_cast<const float4*>(&scale[f4]);
    float4 sh = *reinterpret_cast<const float4*>(&shiftv[f4]);
    v.x = fmaxf(0.f, fmaf(v.x, sc.x, sh.x));
    v.y = fmaxf(0.f, fmaf(v.y, sc.y, sh.y));
    v.z = fmaxf(0.f, fmaf(v.z, sc.z, sh.z));
    v.w = fmaxf(0.f, fmaf(v.w, sc.w, sh.w));
    reinterpret_cast<float4*>(y)[i] = v;
  }
}

extern "C" void kernel_launch(void* const* d_in, const int* in_sizes, int n_in,
                              void* d_out, int out_size, void* d_ws, size_t ws_size,
                              hipStream_t stream) {
  const float* node_features = (const float*)d_in[0];
  const float* edges_weight  = (const float*)d_in[1];
  const int*   identities    = (const int*)d_in[2];
  const int*   edge_src      = (const int*)d_in[3];
  const int*   edge_dst      = (const int*)d_in[4];
  const float* pe            = (const float*)d_in[5];
  const float* W0            = (const float*)d_in[6];
  const float* W1            = (const float*)d_in[7];
  const float* g0            = (const float*)d_in[8];
  const float* b0            = (const float*)d_in[9];
  const float* g1            = (const float*)d_in[10];
  const float* b1            = (const float*)d_in[11];

  const int T = in_sizes[2];            // 4
  const int E = in_sizes[3];            // 800000
  const int F = in_sizes[8];            // 64
  const int N = in_sizes[0] / (T * F);  // 50000
  const int R = N * T;                  // 200000

  float* out = (float*)d_out;
  float* out_h = out;                            // (N,T,F) fp32
  float* out_readout = out + (size_t)N * T * F;  // (T,F)

  // ---- workspace layout ----
  char* ws = (char*)d_ws;
  size_t off = 0;
  auto alloc = [&](size_t bytes) -> void* {
    off = (off + 255) & ~(size_t)255;
    void* p = ws + off;
    off += bytes;
    return p;
  };
  int*    indeg    = (int*)alloc((size_t)N * sizeof(int));
  int*    partials = (int*)alloc(64 * sizeof(int));
  int*    base_    = (int*)alloc(64 * sizeof(int));
  int*    offsets  = (int*)alloc(((size_t)N + 1) * sizeof(int));
  int*    cursor   = (int*)alloc((size_t)N * sizeof(int));
  int*    csr_src  = (int*)alloc((size_t)E * sizeof(int));
  float4* csr_w    = (float4*)alloc((size_t)E * sizeof(float4));
  unsigned short* h0b  = (unsigned short*)alloc((size_t)N * TF * 2);  // reused as y0b
  unsigned short* aggb = (unsigned short*)alloc((size_t)N * TF * 2);
  short* wf0 = (short*)alloc(8 * 512 * sizeof(short));
  short* wf1 = (short*)alloc(8 * 512 * sizeof(short));
  const int MMB = 512;  // mfma matmul grid
  float* mm_part = (float*)alloc((size_t)MMB * 320 * sizeof(float));
  float* red     = (float*)alloc(320 * sizeof(float));
  float* scale0 = (float*)alloc(64 * sizeof(float));
  float* shift0 = (float*)alloc(64 * sizeof(float));
  float* scale1 = (float*)alloc(64 * sizeof(float));
  float* shift1 = (float*)alloc(64 * sizeof(float));
  (void)ws_size;

  const int nb = (N + 1023) / 1024;  // <=64

  // ---- CSR build ----
  hipLaunchKernelGGL(zero_kernel, dim3((N + 255) / 256), dim3(256), 0, stream, indeg, N);
  hipLaunchKernelGGL(hist_kernel, dim3((E + 255) / 256), dim3(256), 0, stream, edge_dst, indeg, E);
  hipLaunchKernelGGL(scan_part1, dim3(nb), dim3(1024), 0, stream, indeg, partials, N);
  hipLaunchKernelGGL(scan_part2, dim3(1), dim3(64), 0, stream, partials, base_, offsets, nb, N);
  hipLaunchKernelGGL(scan_part3, dim3(nb), dim3(1024), 0, stream, indeg, base_, offsets, cursor, N);
  hipLaunchKernelGGL(fill_kernel, dim3((E + 255) / 256), dim3(256), 0, stream,
                     edge_src, edge_dst, edges_weight, cursor, csr_src, csr_w, E);

  // ---- W fragments + prep ----
  hipLaunchKernelGGL(wfrag_kernel, dim3(1), dim3(512), 0, stream, W0, W1, wf0, wf1);
  hipLaunchKernelGGL(prep_kernel, dim3(2048), dim3(256), 0, stream,
                     node_features, pe, identities, (uint2*)h0b, (N * TF) / 4);

  const int agg_blocks = (N + 3) / 4;

  // ---- layer 0 ----
  hipLaunchKernelGGL((aggregate_kernel<0>), dim3(agg_blocks), dim3(256), 0, stream,
                     (const uint2*)h0b, offsets, csr_src, (const float*)csr_w,
                     nullptr, nullptr, (uint2*)aggb, N);
  hipLaunchKernelGGL((mfma_matmul_kernel<0>), dim3(MMB), dim3(256), 0, stream,
                     aggb, wf0, h0b /*y0b*/, nullptr, mm_part, R);
  hipLaunchKernelGGL(reduce_part_kernel, dim3(20), dim3(1024), 0, stream, mm_part, red, MMB);
  hipLaunchKernelGGL(bn_from_red_kernel, dim3(1), dim3(64), 0, stream,
                     red, g0, b0, scale0, shift0, 1.0f / (float)R);

  // ---- layer 1 (BN0+ReLU fused into gather) ----
  hipLaunchKernelGGL((aggregate_kernel<1>), dim3(agg_blocks), dim3(256), 0, stream,
                     (const uint2*)h0b /*y0b*/, offsets, csr_src, (const float*)csr_w,
                     scale0, shift0, (uint2*)aggb, N);
  hipLaunchKernelGGL((mfma_matmul_kernel<1>), dim3(MMB), dim3(256), 0, stream,
                     aggb, wf1, nullptr, out_h, mm_part, R);
  hipLaunchKernelGGL(reduce_part_kernel, dim3(20), dim3(1024), 0, stream, mm_part, red, MMB);
  hipLaunchKernelGGL(finalize_from_red_kernel, dim3(1), dim3(256), 0, stream,
                     red, g1, b1, scale1, shift1, 1.0f / (float)R,
                     out_readout, 1.0f / (float)N);

  // ---- final BN1 + ReLU in place ----
  hipLaunchKernelGGL(bn_relu_kernel, dim3(2048), dim3(256), 0, stream,
                     out_h, scale1, shift1, (R * F) >> 2);
}

// Round 5
// 285.026 us; speedup vs baseline: 2.6746x; 1.0370x over previous
//
#include <hip/hip_runtime.h>

// Shapes fixed by the reference: T=4, F=64, row = T*F = 256 elems (512 B bf16).
#define TF 256

typedef __attribute__((ext_vector_type(8))) short short8;
typedef __attribute__((ext_vector_type(4))) float f32x4;

// ---------- bf16 helpers (fp32 <-> bf16, RNE) ----------
__device__ inline unsigned short f2bf(float x) {
  unsigned u = __float_as_uint(x);
  u += 0x7fffu + ((u >> 16) & 1u);
  return (unsigned short)(u >> 16);
}
__device__ inline unsigned pack2(unsigned short lo, unsigned short hi) {
  return (unsigned)lo | ((unsigned)hi << 16);
}
__device__ inline float bflo(unsigned u) { return __uint_as_float(u << 16); }
__device__ inline float bfhi(unsigned u) { return __uint_as_float(u & 0xffff0000u); }

__global__ void zero_kernel(int* __restrict__ p, int n) {
  int i = blockIdx.x * blockDim.x + threadIdx.x;
  if (i < n) p[i] = 0;
}

__global__ void hist_kernel(const int* __restrict__ dst, int* __restrict__ indeg, int E) {
  int e = blockIdx.x * blockDim.x + threadIdx.x;
  if (e < E) atomicAdd(&indeg[dst[e]], 1);
}

// ---------- hierarchical scan ----------
__global__ __launch_bounds__(1024) void scan_part1(const int* __restrict__ indeg,
                                                   int* __restrict__ partials, int n) {
  __shared__ int wsum[16];
  const int tid = threadIdx.x;
  const int lane = tid & 63;
  const int wid = tid >> 6;
  int i = blockIdx.x * 1024 + tid;
  int s = (i < n) ? indeg[i] : 0;
  #pragma unroll
  for (int o = 1; o < 64; o <<= 1) s += __shfl_xor(s, o, 64);
  if (lane == 0) wsum[wid] = s;
  __syncthreads();
  if (tid == 0) {
    int acc = 0;
    #pragma unroll
    for (int w = 0; w < 16; ++w) acc += wsum[w];
    partials[blockIdx.x] = acc;
  }
}

__global__ __launch_bounds__(64) void scan_part2(const int* __restrict__ partials,
                                                 int* __restrict__ base,
                                                 int* __restrict__ offsets, int nb, int n) {
  const int i = threadIdx.x;
  int v = (i < nb) ? partials[i] : 0;
  int s = v;
  #pragma unroll
  for (int o = 1; o < 64; o <<= 1) {
    int t = __shfl_up(s, o, 64);
    if (i >= o) s += t;
  }
  if (i < nb) base[i] = s - v;
  if (i == nb - 1) offsets[n] = s;
}

__global__ __launch_bounds__(1024) void scan_part3(const int* __restrict__ indeg,
                                                   const int* __restrict__ base,
                                                   int* __restrict__ offsets,
                                                   int* __restrict__ cursor, int n) {
  __shared__ int wsum[16];
  const int tid = threadIdx.x;
  const int lane = tid & 63;
  const int wid = tid >> 6;
  int i = blockIdx.x * 1024 + tid;
  int v = (i < n) ? indeg[i] : 0;
  int s = v;
  #pragma unroll
  for (int o = 1; o < 64; o <<= 1) {
    int t = __shfl_up(s, o, 64);
    if (lane >= o) s += t;
  }
  if (lane == 63) wsum[wid] = s;
  __syncthreads();
  if (tid == 0) {
    int acc = 0;
    #pragma unroll
    for (int w = 0; w < 16; ++w) { int t = wsum[w]; wsum[w] = acc; acc += t; }
  }
  __syncthreads();
  int excl = s - v + wsum[wid] + base[blockIdx.x];
  if (i < n) { offsets[i] = excl; cursor[i] = excl; }
}

// scatter edges into CSR slots; src stored as BYTE offset (src*512) for 32-bit addressing
__global__ void fill_kernel(const int* __restrict__ src, const int* __restrict__ dst,
                            const float* __restrict__ ew, int* __restrict__ cursor,
                            int* __restrict__ csr_srcB, float4* __restrict__ csr_w, int E) {
  int e = blockIdx.x * blockDim.x + threadIdx.x;
  if (e >= E) return;
  int d = dst[e];
  int pos = atomicAdd(&cursor[d], 1);
  csr_srcB[pos] = src[e] << 9;  // row byte offset
  float4 w;
  w.x = ew[0 * E + e];
  w.y = ew[1 * E + e];
  w.z = ew[2 * E + e];
  w.w = ew[3 * E + e];
  csr_w[pos] = w;
}

// h0_bf16 = bf16(node_features + pe[identities[t]]); 4 elems/thread
__global__ void prep_kernel(const float* __restrict__ x, const float* __restrict__ pe,
                            const int* __restrict__ ids, uint2* __restrict__ h0, int n4) {
  int i = blockIdx.x * blockDim.x + threadIdx.x;
  const int stride = gridDim.x * blockDim.x;
  for (; i < n4; i += stride) {
    int e0 = (i << 2) & (TF - 1);
    int t = e0 >> 6;
    int f4 = e0 & 63;
    float4 v = reinterpret_cast<const float4*>(x)[i];
    float4 p = *reinterpret_cast<const float4*>(&pe[ids[t] * 64 + f4]);
    uint2 o;
    o.x = pack2(f2bf(v.x + p.x), f2bf(v.y + p.y));
    o.y = pack2(f2bf(v.z + p.z), f2bf(v.w + p.w));
    h0[i] = o;
  }
}

// One wave per node; 32 lanes cover one 512 B row (uint4 = 16 B/lane), so the wave
// processes TWO edges per iteration (p = lane>>5 picks the edge). Unrolled x2 ->
// 4 edges, 2 independent src->row load chains in flight. shfl_xor(32) combines
// even/odd-edge partials at the end.
// LAYER 1 applies relu(y*scale+shift) (layer-0 BN) to gathered values on the fly.
template <int LAYER>
__global__ __launch_bounds__(256) void aggregate_kernel(
    const char* __restrict__ h_base, const int* __restrict__ offsets,
    const int* __restrict__ csr_srcB, const float* __restrict__ csr_w,
    const float* __restrict__ scale, const float* __restrict__ shiftv,
    uint4* __restrict__ agg, int n_nodes) {
  const int lane = threadIdx.x & 63;
  const int wid = threadIdx.x >> 6;
  const int v = blockIdx.x * 4 + wid;
  if (v >= n_nodes) return;
  const int p = lane >> 5;         // which edge of the pair
  const unsigned q = lane & 31;    // 16B chunk within the row
  const unsigned qb = q << 4;      // byte offset within row
  const int tw = q >> 3;           // time index for the weight

  float sc[8], sh[8];
  if (LAYER == 1) {
    const int f0 = (q & 7) << 3;
    #pragma unroll
    for (int j = 0; j < 8; ++j) { sc[j] = scale[f0 + j]; sh[j] = shiftv[f0 + j]; }
  }

  float acc[8];
  #pragma unroll
  for (int j = 0; j < 8; ++j) acc[j] = 0.f;

  auto body = [&](uint4 u, float w) {
    float x[8] = {bflo(u.x), bfhi(u.x), bflo(u.y), bfhi(u.y),
                  bflo(u.z), bfhi(u.z), bflo(u.w), bfhi(u.w)};
    #pragma unroll
    for (int j = 0; j < 8; ++j) {
      float t = x[j];
      if (LAYER == 1) t = fmaxf(0.f, fmaf(t, sc[j], sh[j]));
      acc[j] = fmaf(w, t, acc[j]);
    }
  };

  const int beg = offsets[v];
  const int end = offsets[v + 1];
  int i = beg;
  for (; i + 4 <= end; i += 4) {
    const int e0 = i + p;
    const int e1 = i + 2 + p;
    const unsigned s0 = (unsigned)csr_srcB[e0];
    const unsigned s1 = (unsigned)csr_srcB[e1];
    const float w0 = csr_w[e0 * 4 + tw];
    const float w1 = csr_w[e1 * 4 + tw];
    const uint4 u0 = *reinterpret_cast<const uint4*>(h_base + (s0 + qb));
    const uint4 u1 = *reinterpret_cast<const uint4*>(h_base + (s1 + qb));
    body(u0, w0);
    body(u1, w1);
  }
  for (; i < end; i += 2) {  // remainder: pair with w=0 masking for the overhang
    const int ee = i + p;
    const int e = ee < end ? ee : end - 1;
    float w = csr_w[e * 4 + tw];
    if (ee >= end) w = 0.f;
    const unsigned s = (unsigned)csr_srcB[e];
    const uint4 u = *reinterpret_cast<const uint4*>(h_base + (s + qb));
    body(u, w);
  }

  #pragma unroll
  for (int j = 0; j < 8; ++j) acc[j] += __shfl_xor(acc[j], 32, 64);
  if (lane < 32) {
    uint4 o;
    o.x = pack2(f2bf(acc[0]), f2bf(acc[1]));
    o.y = pack2(f2bf(acc[2]), f2bf(acc[3]));
    o.z = pack2(f2bf(acc[4]), f2bf(acc[5]));
    o.w = pack2(f2bf(acc[6]), f2bf(acc[7]));
    agg[(size_t)v * 32 + q] = o;
  }
}

// Pre-pack W (fp32 64x64) into MFMA B-fragment layout as bf16.
__global__ __launch_bounds__(512) void wfrag_kernel(const float* __restrict__ W0,
                                                    const float* __restrict__ W1,
                                                    short* __restrict__ wf0,
                                                    short* __restrict__ wf1) {
  const int frag = threadIdx.x >> 6, lane = threadIdx.x & 63;
  const int c = frag >> 1, h = frag & 1;
  const int n = (c << 4) + (lane & 15);
  const int k0 = h * 32 + ((lane >> 4) << 3);
  short* o0 = wf0 + frag * 512 + lane * 8;
  short* o1 = wf1 + frag * 512 + lane * 8;
  #pragma unroll
  for (int i = 0; i < 8; ++i) {
    o0[i] = (short)f2bf(W0[(k0 + i) * 64 + n]);
    o1[i] = (short)f2bf(W1[(k0 + i) * 64 + n]);
  }
}

// y[r,f] = agg_bf16[r,:] @ W ; 8 MFMAs per 16-row block per wave; y stored bf16.
// Emits per-block partials: part[blk*320 + t*64+f] = sum_rows y, part[blk*320+256+f] = sum y^2.
__global__ __launch_bounds__(256) void mfma_matmul_kernel(
    const unsigned short* __restrict__ aggb, const short* __restrict__ wf,
    unsigned short* __restrict__ y_bf, float* __restrict__ part, int R) {
  const int tid = threadIdx.x;
  const int lane = tid & 63;
  const int wid = tid >> 6;

  short8 bfr[8];
  #pragma unroll
  for (int g = 0; g < 8; ++g)
    bfr[g] = *reinterpret_cast<const short8*>(wf + g * 512 + lane * 8);

  f32x4 csum[4];
  float ssq[4];
  #pragma unroll
  for (int c = 0; c < 4; ++c) { csum[c] = (f32x4){0.f, 0.f, 0.f, 0.f}; ssq[c] = 0.f; }

  const int nrb = (R + 15) >> 4;
  const int k0 = (lane >> 4) << 3;
  for (int rb = blockIdx.x * 4 + wid; rb < nrb; rb += gridDim.x * 4) {
    const int base = rb << 4;
    const int row = base + (lane & 15);
    short8 a0 = (short8){0, 0, 0, 0, 0, 0, 0, 0};
    short8 a1 = a0;
    if (row < R) {
      const short8* ap = reinterpret_cast<const short8*>(aggb + (size_t)row * 64 + k0);
      a0 = ap[0];
      a1 = ap[4];
    }
    f32x4 acc[4];
    #pragma unroll
    for (int c = 0; c < 4; ++c) {
      acc[c] = (f32x4){0.f, 0.f, 0.f, 0.f};
      acc[c] = __builtin_amdgcn_mfma_f32_16x16x32_bf16(a0, bfr[c * 2 + 0], acc[c], 0, 0, 0);
      acc[c] = __builtin_amdgcn_mfma_f32_16x16x32_bf16(a1, bfr[c * 2 + 1], acc[c], 0, 0, 0);
    }
    const int rbase = base + ((lane >> 4) << 2);
    #pragma unroll
    for (int c = 0; c < 4; ++c) {
      const int col = (c << 4) + (lane & 15);
      #pragma unroll
      for (int i = 0; i < 4; ++i) {
        const int r2 = rbase + i;
        if (r2 < R) {
          const float val = acc[c][i];
          y_bf[(size_t)r2 * 64 + col] = f2bf(val);
          csum[c][i] += val;
          ssq[c] += val * val;
        }
      }
    }
  }

  #pragma unroll
  for (int c = 0; c < 4; ++c) {
    #pragma unroll
    for (int i = 0; i < 4; ++i) {
      float v = csum[c][i];
      v += __shfl_xor(v, 16, 64);
      v += __shfl_xor(v, 32, 64);
      csum[c][i] = v;
    }
    float q = ssq[c];
    q += __shfl_xor(q, 16, 64);
    q += __shfl_xor(q, 32, 64);
    ssq[c] = q;
  }
  __shared__ float lcs[4][256];
  __shared__ float lsq[4][64];
  if (lane < 16) {
    #pragma unroll
    for (int c = 0; c < 4; ++c) {
      #pragma unroll
      for (int i = 0; i < 4; ++i) lcs[wid][i * 64 + (c << 4) + lane] = csum[c][i];
      lsq[wid][(c << 4) + lane] = ssq[c];
    }
  }
  __syncthreads();
  float s = lcs[0][tid] + lcs[1][tid] + lcs[2][tid] + lcs[3][tid];
  part[(size_t)blockIdx.x * 320 + tid] = s;
  if (tid < 64)
    part[(size_t)blockIdx.x * 320 + 256 + tid] =
        lsq[0][tid] + lsq[1][tid] + lsq[2][tid] + lsq[3][tid];
}

// Parallel deterministic reduce of part[nblk][320] -> red[320].
__global__ __launch_bounds__(1024) void reduce_part_kernel(const float* __restrict__ part,
                                                           float* __restrict__ red, int nblk) {
  __shared__ float lds[1024];
  const int tid = threadIdx.x;
  const int col = blockIdx.x * 16 + (tid & 15);
  const int r = tid >> 4;  // 0..63
  float s = 0.f;
  for (int bk = r; bk < nblk; bk += 64) s += part[(size_t)bk * 320 + col];
  lds[tid] = s;
  __syncthreads();
  #pragma unroll
  for (int off = 512; off >= 16; off >>= 1) {
    if (tid < off) lds[tid] += lds[tid + off];
    __syncthreads();
  }
  if (tid < 16) red[col] = lds[tid];
}

// layer-0 BN params from red[320]
__global__ __launch_bounds__(64) void bn_from_red_kernel(
    const float* __restrict__ red, const float* __restrict__ g, const float* __restrict__ b,
    float* __restrict__ scale, float* __restrict__ shiftv, float inv_count) {
  const int f = threadIdx.x;
  float sum = red[f] + red[64 + f] + red[128 + f] + red[192 + f];
  float mean = sum * inv_count;
  float var = red[256 + f] * inv_count - mean * mean;
  float sc = g[f] * rsqrtf(var + 1e-5f);
  scale[f] = sc;
  shiftv[f] = fmaf(-mean, sc, b[f]);
}

// layer-1: readout = red[0:256]/N (mean(agg)@W == mean(agg@W)) + BN params
__global__ __launch_bounds__(256) void finalize_from_red_kernel(
    const float* __restrict__ red, const float* __restrict__ g, const float* __restrict__ b,
    float* __restrict__ scale, float* __restrict__ shiftv, float inv_count,
    float* __restrict__ out_readout, float invN) {
  const int tid = threadIdx.x;
  out_readout[tid] = red[tid] * invN;
  if (tid < 64) {
    float sum = red[tid] + red[64 + tid] + red[128 + tid] + red[192 + tid];
    float mean = sum * inv_count;
    float var = red[256 + tid] * inv_count - mean * mean;
    float sc = g[tid] * rsqrtf(var + 1e-5f);
    scale[tid] = sc;
    shiftv[tid] = fmaf(-mean, sc, b[tid]);
  }
}

// final: out_fp32 = relu(y1_bf16 * scale + shift); 8 elems/thread
__global__ void bn_relu_out_kernel(const uint4* __restrict__ yb,
                                   const float* __restrict__ scale,
                                   const float* __restrict__ shiftv,
                                   float4* __restrict__ out, int n8) {
  int i = blockIdx.x * blockDim.x + threadIdx.x;
  if (i >= n8) return;
  const int f0 = (i & 7) << 3;
  uint4 u = yb[i];
  float x[8] = {bflo(u.x), bfhi(u.x), bflo(u.y), bfhi(u.y),
                bflo(u.z), bfhi(u.z), bflo(u.w), bfhi(u.w)};
  float4 o0, o1;
  o0.x = fmaxf(0.f, fmaf(x[0], scale[f0 + 0], shiftv[f0 + 0]));
  o0.y = fmaxf(0.f, fmaf(x[1], scale[f0 + 1], shiftv[f0 + 1]));
  o0.z = fmaxf(0.f, fmaf(x[2], scale[f0 + 2], shiftv[f0 + 2]));
  o0.w = fmaxf(0.f, fmaf(x[3], scale[f0 + 3], shiftv[f0 + 3]));
  o1.x = fmaxf(0.f, fmaf(x[4], scale[f0 + 4], shiftv[f0 + 4]));
  o1.y = fmaxf(0.f, fmaf(x[5], scale[f0 + 5], shiftv[f0 + 5]));
  o1.z = fmaxf(0.f, fmaf(x[6], scale[f0 + 6], shiftv[f0 + 6]));
  o1.w = fmaxf(0.f, fmaf(x[7], scale[f0 + 7], shiftv[f0 + 7]));
  out[i * 2 + 0] = o0;
  out[i * 2 + 1] = o1;
}

extern "C" void kernel_launch(void* const* d_in, const int* in_sizes, int n_in,
                              void* d_out, int out_size, void* d_ws, size_t ws_size,
                              hipStream_t stream) {
  const float* node_features = (const float*)d_in[0];
  const float* edges_weight  = (const float*)d_in[1];
  const int*   identities    = (const int*)d_in[2];
  const int*   edge_src      = (const int*)d_in[3];
  const int*   edge_dst      = (const int*)d_in[4];
  const float* pe            = (const float*)d_in[5];
  const float* W0            = (const float*)d_in[6];
  const float* W1            = (const float*)d_in[7];
  const float* g0            = (const float*)d_in[8];
  const float* b0            = (const float*)d_in[9];
  const float* g1            = (const float*)d_in[10];
  const float* b1            = (const float*)d_in[11];

  const int T = in_sizes[2];            // 4
  const int E = in_sizes[3];            // 800000
  const int F = in_sizes[8];            // 64
  const int N = in_sizes[0] / (T * F);  // 50000
  const int R = N * T;                  // 200000

  float* out = (float*)d_out;
  float* out_h = out;                            // (N,T,F) fp32
  float* out_readout = out + (size_t)N * T * F;  // (T,F)

  // ---- workspace layout ----
  char* ws = (char*)d_ws;
  size_t off = 0;
  auto alloc = [&](size_t bytes) -> void* {
    off = (off + 255) & ~(size_t)255;
    void* p = ws + off;
    off += bytes;
    return p;
  };
  int*    indeg    = (int*)alloc((size_t)N * sizeof(int));
  int*    partials = (int*)alloc(64 * sizeof(int));
  int*    base_    = (int*)alloc(64 * sizeof(int));
  int*    offsets  = (int*)alloc(((size_t)N + 1) * sizeof(int));
  int*    cursor   = (int*)alloc((size_t)N * sizeof(int));
  int*    csr_srcB = (int*)alloc((size_t)E * sizeof(int));
  float4* csr_w    = (float4*)alloc((size_t)E * sizeof(float4));
  unsigned short* h0b  = (unsigned short*)alloc((size_t)N * TF * 2);  // h0 -> y0 -> y1
  unsigned short* aggb = (unsigned short*)alloc((size_t)N * TF * 2);
  short* wf0 = (short*)alloc(8 * 512 * sizeof(short));
  short* wf1 = (short*)alloc(8 * 512 * sizeof(short));
  const int MMB = 256;  // mfma matmul grid
  float* mm_part = (float*)alloc((size_t)MMB * 320 * sizeof(float));
  float* red     = (float*)alloc(320 * sizeof(float));
  float* scale0 = (float*)alloc(64 * sizeof(float));
  float* shift0 = (float*)alloc(64 * sizeof(float));
  float* scale1 = (float*)alloc(64 * sizeof(float));
  float* shift1 = (float*)alloc(64 * sizeof(float));
  (void)ws_size;

  const int nb = (N + 1023) / 1024;  // <=64

  // ---- CSR build ----
  hipLaunchKernelGGL(zero_kernel, dim3((N + 255) / 256), dim3(256), 0, stream, indeg, N);
  hipLaunchKernelGGL(hist_kernel, dim3((E + 255) / 256), dim3(256), 0, stream, edge_dst, indeg, E);
  hipLaunchKernelGGL(scan_part1, dim3(nb), dim3(1024), 0, stream, indeg, partials, N);
  hipLaunchKernelGGL(scan_part2, dim3(1), dim3(64), 0, stream, partials, base_, offsets, nb, N);
  hipLaunchKernelGGL(scan_part3, dim3(nb), dim3(1024), 0, stream, indeg, base_, offsets, cursor, N);
  hipLaunchKernelGGL(fill_kernel, dim3((E + 255) / 256), dim3(256), 0, stream,
                     edge_src, edge_dst, edges_weight, cursor, csr_srcB, csr_w, E);

  // ---- W fragments + prep ----
  hipLaunchKernelGGL(wfrag_kernel, dim3(1), dim3(512), 0, stream, W0, W1, wf0, wf1);
  hipLaunchKernelGGL(prep_kernel, dim3(2048), dim3(256), 0, stream,
                     node_features, pe, identities, (uint2*)h0b, (N * TF) / 4);

  const int agg_blocks = (N + 3) / 4;

  // ---- layer 0 ----
  hipLaunchKernelGGL((aggregate_kernel<0>), dim3(agg_blocks), dim3(256), 0, stream,
                     (const char*)h0b, offsets, csr_srcB, (const float*)csr_w,
                     nullptr, nullptr, (uint4*)aggb, N);
  hipLaunchKernelGGL(mfma_matmul_kernel, dim3(MMB), dim3(256), 0, stream,
                     aggb, wf0, h0b /*y0b*/, mm_part, R);
  hipLaunchKernelGGL(reduce_part_kernel, dim3(20), dim3(1024), 0, stream, mm_part, red, MMB);
  hipLaunchKernelGGL(bn_from_red_kernel, dim3(1), dim3(64), 0, stream,
                     red, g0, b0, scale0, shift0, 1.0f / (float)R);

  // ---- layer 1 (BN0+ReLU fused into gather) ----
  hipLaunchKernelGGL((aggregate_kernel<1>), dim3(agg_blocks), dim3(256), 0, stream,
                     (const char*)h0b /*y0b*/, offsets, csr_srcB, (const float*)csr_w,
                     scale0, shift0, (uint4*)aggb, N);
  hipLaunchKernelGGL(mfma_matmul_kernel, dim3(MMB), dim3(256), 0, stream,
                     aggb, wf1, h0b /*y1b*/, mm_part, R);
  hipLaunchKernelGGL(reduce_part_kernel, dim3(20), dim3(1024), 0, stream, mm_part, red, MMB);
  hipLaunchKernelGGL(finalize_from_red_kernel, dim3(1), dim3(256), 0, stream,
                     red, g1, b1, scale1, shift1, 1.0f / (float)R,
                     out_readout, 1.0f / (float)N);

  // ---- final BN1 + ReLU: out_fp32 = relu(bn(y1_bf16)) ----
  hipLaunchKernelGGL(bn_relu_out_kernel, dim3((R * 8 + 255) / 256), dim3(256), 0, stream,
                     (const uint4*)h0b, scale1, shift1, (float4*)out_h, R * 8);
}